// Round 13
// baseline (496.725 us; speedup 1.0000x reference)
//
#include <hip/hip_runtime.h>

// Binarized MLP forward (512x784 -> 3x6144 -> 10), dual binary/real paths.
// Round 13: GEMM kernel unchanged (r11-validated: counted-vmcnt dbuf + T2
// swizzle + setprio, bank-conflicts=0). Overlap weight-conversion with
// independent compute by job-merging on the single stream:
//  - conv(w2) folded into L1 mix dispatch (is8=2 job; a8/s1 moved to Z1LO
//    region so WV/WS8 writes don't collide)
//  - conv(w3) split across L2 stats_part (z=2) and L2 bn2 (z=2)
//  - prep kernels merged into one launch
//
// Precision plan (validated r1-r12):
//  - layer1 binary: exact i8-digit MFMA, fp64 recombination fused in stats/bn
//  - layer2/3 binary: i8 MFMA K=64, EXACT
//  - real path: fp16 MFMA; all BN stats/normalization in fp64

typedef _Float16 f16x8 __attribute__((ext_vector_type(8)));
typedef _Float16 f16x4 __attribute__((ext_vector_type(4)));
typedef float f32x4 __attribute__((ext_vector_type(4)));
typedef int i32x4 __attribute__((ext_vector_type(4)));

#define MFMA16(a, b, c) __builtin_amdgcn_mfma_f32_16x16x32_f16((a), (b), (c), 0, 0, 0)
#define MFMAI8K64(a, b, c) __builtin_amdgcn_mfma_i32_16x16x64_i8((a), (b), (c), 0, 0, 0)

#define HIDC 6144
#define BATCH 512

// ---- workspace layout (bytes) ----
#define OFF_XH    0ull          // 512x832 fp16                    851,968
#define OFF_A8S1  851968ull     // a8 4x(512x896) + s1 6144x896   7,340,032
#define OFF_SB8   13434880ull   // 512x6144 i8 sign acts         3,145,728
#define OFF_RF    16580608ull   // 512x6144 fp16 real acts       6,291,456
#define OFF_STATS 22872064ull   // 4x6144 fp64                     196,608
#define OFF_PPART 23068672ull   // 2x8x2x6144 fp64               1,572,864
#define OFF_ZPB   24641536ull   // 512x6144 fp32 partial/D0     12,582,912
#define OFF_ZPR   37224448ull   // 512x6144 fp32 partial/D1     12,582,912
#define OFF_ZPR2  49807360ull   // 512x6144 fp32 D2             12,582,912
#define OFF_ZPR3  62390272ull   // 512x6144 fp32 D3             12,582,912
#define OFF_W1V   74973184ull   // 6144x832 fp16                10,223,616
#define OFF_WV    85196800ull   // 6144x6144 fp16               75,497,472
#define OFF_WS8   160694272ull  // 6144x6144 i8 sign weights    37,748,736
#define WS_NEED   198443008ull

#define A8_STRIDE 458752ull     // 512*896 bytes per digit plane

// ---------------------------------------------------------------------------
__device__ __forceinline__ void load_lds16(const void* g, char* lds) {
  __builtin_amdgcn_global_load_lds((const __attribute__((address_space(1))) void*)g,
                                   (__attribute__((address_space(3))) void*)lds, 16, 0, 0);
}

// ---------------------------------------------------------------------------
// fused conv helper: 8 fp32 -> f16x8 + 8 sign bytes
__device__ __forceinline__ void conv8(const float* __restrict__ s,
                                      _Float16* __restrict__ wv,
                                      char* __restrict__ s8, size_t o8) {
  float4 v0 = *(const float4*)(s + o8);
  float4 v1 = *(const float4*)(s + o8 + 4);
  float a[8] = {v0.x, v0.y, v0.z, v0.w, v1.x, v1.y, v1.z, v1.w};
  f16x8 hv;
  unsigned long long sbits = 0;
#pragma unroll
  for (int e = 0; e < 8; ++e) {
    hv[e] = (_Float16)a[e];
    char sg = a[e] > 0.f ? 1 : (a[e] < 0.f ? -1 : 0);
    sbits |= ((unsigned long long)(unsigned char)sg) << (8 * e);
  }
  *(f16x8*)(wv + o8) = hv;
  *(unsigned long long*)(s8 + o8) = sbits;
}

// ---------------------------------------------------------------------------
// merged prep: blocks [0,1792): x -> xh + digit planes; [1792,23296): w1 -> s1,w1v
__global__ __launch_bounds__(256) void k_prep_all(const float* __restrict__ x,
                                                  const float* __restrict__ w,
                                                  char* __restrict__ a8,
                                                  _Float16* __restrict__ xh,
                                                  char* __restrict__ s1,
                                                  _Float16* __restrict__ w1v) {
  if (blockIdx.x < 1792) {
    int idx = blockIdx.x * 256 + threadIdx.x;  // 512*896
    if (idx >= 512 * 896) return;
    int row = idx / 896, k = idx - row * 896;
    float v = (k < 784) ? x[(size_t)row * 784 + k] : 0.f;
    int q = (int)lrintf(v * 16777216.0f);
    int d0 = ((q + 128) & 255) - 128; q = (q - d0) >> 8;
    int d1 = ((q + 128) & 255) - 128; q = (q - d1) >> 8;
    int d2 = ((q + 128) & 255) - 128; q = (q - d2) >> 8;
    a8[idx] = (char)d0;
    a8[A8_STRIDE + idx] = (char)d1;
    a8[2 * A8_STRIDE + idx] = (char)d2;
    a8[3 * A8_STRIDE + idx] = (char)q;  // |q| <= 9
    if (k < 832) xh[(size_t)row * 832 + k] = (_Float16)v;
  } else {
    int idx = (blockIdx.x - 1792) * 256 + threadIdx.x;  // 6144*896
    if (idx >= 6144 * 896) return;
    int r = idx / 896, k = idx - r * 896;
    float v = (k < 784) ? w[(size_t)r * 784 + k] : 0.f;
    s1[idx] = v > 0.f ? 1 : (v < 0.f ? -1 : 0);
    if (k < 832) w1v[(size_t)r * 832 + k] = (_Float16)v;
  }
}

// ---------------------------------------------------------------------------
// Mixed GEMM dispatch, 128x128 tile, 256 threads (4 waves 2x2), double-
// buffered LDS, counted-vmcnt pipeline, XOR-swizzled LDS (r11-validated).
//   is8=1: BK=128 i8 GEMM ; is8=0: BK=64 f16 GEMM
//   is8=2: weight-conversion job: A=fp32 src, B=wv dst, C=ws8 dst
struct MixJob {
  const void* A;
  const void* B;
  float* C;
  int K;
  int kstart;
  int ksteps;
  int is8;
};
struct Mix6 { MixJob j[6]; };

__global__ __launch_bounds__(256) void k_gemm_mix(Mix6 P) {
  __shared__ __align__(16) char smem[65536];  // 2 x {A@0 16K, B@16384 16K}
  MixJob J = P.j[0];
  if (blockIdx.z == 1) J = P.j[1];
  if (blockIdx.z == 2) J = P.j[2];
  if (blockIdx.z == 3) J = P.j[3];
  if (blockIdx.z == 4) J = P.j[4];
  if (blockIdx.z == 5) J = P.j[5];
  const int t = threadIdx.x;
  const int lane = t & 63, wid = t >> 6;
  const int wm = wid >> 1, wn = wid & 1;
  const int bn = blockIdx.x, bm = blockIdx.y;
  const size_t K = (size_t)J.K;
  const int nt = J.ksteps;

  if (J.is8 == 2) {
    // ---------------- conv job: 6144^2 fp32 -> fp16 + i8 sign ----------------
    const float* srcw = (const float*)J.A;
    _Float16* wvo = (_Float16*)J.B;
    char* s8o = (char*)J.C;
    int bid = bm * 48 + bn;  // 0..191
    for (int i = 0; i < 96; ++i) {
      size_t g8 = ((size_t)bid * 96 + i) * 256 + t;  // 192*96*256 = 4,718,592
      conv8(srcw, wvo, s8o, g8 * 8);
    }
    return;
  }

  if (J.is8 == 1) {
    // ---------------- i8 path (BK=128) ----------------
    const char* A = (const char*)J.A;
    const char* B = (const char*)J.B;
    i32x4 acc[4][4];
#pragma unroll
    for (int mf = 0; mf < 4; ++mf)
#pragma unroll
      for (int nf = 0; nf < 4; ++nf) acc[mf][nf] = (i32x4){0, 0, 0, 0};

    auto stage = [&](char* dst, int k0) {
#pragma unroll
      for (int i = 0; i < 4; ++i) {
        int p = i * 256 + t;
        int r = p >> 3, c = p & 7;
        int cs = c ^ (r & 7);
        load_lds16(A + (size_t)(bm * 128 + r) * K + k0 + cs * 16, dst + p * 16);
      }
#pragma unroll
      for (int i = 0; i < 4; ++i) {
        int p = i * 256 + t;
        int r = p >> 3, c = p & 7;
        int cs = c ^ (r & 7);
        load_lds16(B + (size_t)(bn * 128 + r) * K + k0 + cs * 16, dst + 16384 + p * 16);
      }
    };

    stage(smem, J.kstart);
    for (int kt = 0; kt < nt; ++kt) {
      char* cbuf = smem + (kt & 1) * 32768;
      char* nbuf = smem + ((kt + 1) & 1) * 32768;
      if (kt + 1 < nt) {
        stage(nbuf, J.kstart + (kt + 1) * 128);
        asm volatile("s_waitcnt vmcnt(8)" ::: "memory");
      } else {
        asm volatile("s_waitcnt vmcnt(0)" ::: "memory");
      }
      __builtin_amdgcn_s_barrier();
      __builtin_amdgcn_s_setprio(1);
#pragma unroll
      for (int kk = 0; kk < 2; ++kk) {  // two K=64 halves of BK=128
        i32x4 av[4], bv[4];
#pragma unroll
        for (int mf = 0; mf < 4; ++mf) {
          int r = wm * 64 + mf * 16 + (lane & 15);
          int bo = (r * 128 + kk * 64 + (lane >> 4) * 16) ^ ((r & 7) << 4);
          av[mf] = *(const i32x4*)(cbuf + bo);
        }
#pragma unroll
        for (int nf = 0; nf < 4; ++nf) {
          int r = wn * 64 + nf * 16 + (lane & 15);
          int bo = (r * 128 + kk * 64 + (lane >> 4) * 16) ^ ((r & 7) << 4);
          bv[nf] = *(const i32x4*)(cbuf + 16384 + bo);
        }
#pragma unroll
        for (int mf = 0; mf < 4; ++mf)
#pragma unroll
          for (int nf = 0; nf < 4; ++nf) acc[mf][nf] = MFMAI8K64(av[mf], bv[nf], acc[mf][nf]);
      }
      __builtin_amdgcn_s_setprio(0);
      __builtin_amdgcn_s_barrier();
    }
#pragma unroll
    for (int mf = 0; mf < 4; ++mf)
#pragma unroll
      for (int nf = 0; nf < 4; ++nf) {
        int col = bn * 128 + wn * 64 + nf * 16 + (lane & 15);
        int row0 = bm * 128 + wm * 64 + mf * 16 + ((lane >> 4) << 2);
#pragma unroll
        for (int rr = 0; rr < 4; ++rr) {
          J.C[(size_t)(row0 + rr) * HIDC + col] = (float)acc[mf][nf][rr];  // exact (<2^24)
        }
      }
  } else {
    // ---------------- f16 path (BK=64) ----------------
    const _Float16* A = (const _Float16*)J.A;
    const _Float16* B = (const _Float16*)J.B;
    f32x4 acc[4][4];
#pragma unroll
    for (int mf = 0; mf < 4; ++mf)
#pragma unroll
      for (int nf = 0; nf < 4; ++nf) acc[mf][nf] = (f32x4){0.f, 0.f, 0.f, 0.f};

    auto stage = [&](char* dst, int k0) {
#pragma unroll
      for (int i = 0; i < 4; ++i) {
        int p = i * 256 + t;
        int r = p >> 3, c = p & 7;
        int cs = c ^ (r & 7);
        load_lds16(A + (size_t)(bm * 128 + r) * K + k0 + cs * 8, dst + p * 16);
      }
#pragma unroll
      for (int i = 0; i < 4; ++i) {
        int p = i * 256 + t;
        int r = p >> 3, c = p & 7;
        int cs = c ^ (r & 7);
        load_lds16(B + (size_t)(bn * 128 + r) * K + k0 + cs * 8, dst + 16384 + p * 16);
      }
    };

    stage(smem, J.kstart);
    for (int kt = 0; kt < nt; ++kt) {
      char* cbuf = smem + (kt & 1) * 32768;
      char* nbuf = smem + ((kt + 1) & 1) * 32768;
      if (kt + 1 < nt) {
        stage(nbuf, J.kstart + (kt + 1) * 64);
        asm volatile("s_waitcnt vmcnt(8)" ::: "memory");
      } else {
        asm volatile("s_waitcnt vmcnt(0)" ::: "memory");
      }
      __builtin_amdgcn_s_barrier();
      __builtin_amdgcn_s_setprio(1);
#pragma unroll
      for (int kk = 0; kk < 2; ++kk) {
        f16x8 av[4], bv[4];
#pragma unroll
        for (int mf = 0; mf < 4; ++mf) {
          int r = wm * 64 + mf * 16 + (lane & 15);
          int bo = (r * 128 + kk * 64 + (lane >> 4) * 16) ^ ((r & 7) << 4);
          av[mf] = *(const f16x8*)(cbuf + bo);
        }
#pragma unroll
        for (int nf = 0; nf < 4; ++nf) {
          int r = wn * 64 + nf * 16 + (lane & 15);
          int bo = (r * 128 + kk * 64 + (lane >> 4) * 16) ^ ((r & 7) << 4);
          bv[nf] = *(const f16x8*)(cbuf + 16384 + bo);
        }
#pragma unroll
        for (int mf = 0; mf < 4; ++mf)
#pragma unroll
          for (int nf = 0; nf < 4; ++nf) acc[mf][nf] = MFMA16(av[mf], bv[nf], acc[mf][nf]);
      }
      __builtin_amdgcn_s_setprio(0);
      __builtin_amdgcn_s_barrier();
    }
#pragma unroll
    for (int mf = 0; mf < 4; ++mf)
#pragma unroll
      for (int nf = 0; nf < 4; ++nf) {
        int col = bn * 128 + wn * 64 + nf * 16 + (lane & 15);
        int row0 = bm * 128 + wm * 64 + mf * 16 + ((lane >> 4) << 2);
#pragma unroll
        for (int rr = 0; rr < 4; ++rr) {
          J.C[(size_t)(row0 + rr) * HIDC + col] = acc[mf][nf][rr];
        }
      }
  }
}

// ---------------------------------------------------------------------------
// Two-stage per-column stats (mean, rstd over 512 rows), fp64.
// digitmode: v = (((Z3*256+Z2)*256+Z1)*256+Z0) * 2^-24 (planes in Z,Zp0..2)
// Optional conv slice at blockIdx.z==2 (first half of w3 conversion).
struct StJob { const float* Z; const float* Zp0; const float* Zp1; const float* Zp2;
               const float* msk; int digitmode; };
struct St2 { StJob j[2]; const float* bias; int dodrop; double* ppart;
             const float* wsrc; _Float16* wvdst; char* s8dst; };

__global__ __launch_bounds__(256) void k_stats_part(St2 P) {
  const int z = blockIdx.z;
  if (z == 2) {
    // conv(w3) first half: vec8 [0, 2359296)
    int bid = blockIdx.y * 96 + blockIdx.x;  // 0..767
    for (int i = 0; i < 12; ++i) {
      size_t g8 = ((size_t)bid * 12 + i) * 256 + threadIdx.x;  // 768*12*256
      conv8(P.wsrc, P.wvdst, P.s8dst, g8 * 8);
    }
    return;
  }
  __shared__ double sm[4][64];
  __shared__ double sq[4][64];
  StJob J = z ? P.j[1] : P.j[0];
  const int li = threadIdx.x & 63, rg = threadIdx.x >> 6;
  const int col = blockIdx.x * 64 + li;
  const double bb = P.dodrop ? (double)P.bias[col] : 0.0;
  double s = 0.0, s2 = 0.0;
#pragma unroll 4
  for (int rr = 0; rr < 16; ++rr) {
    int r = blockIdx.y * 64 + rg * 16 + rr;
    size_t i = (size_t)r * HIDC + col;
    double v;
    if (J.digitmode) {
      double d0 = (double)J.Z[i], d1 = (double)J.Zp0[i];
      double d2 = (double)J.Zp1[i], d3 = (double)J.Zp2[i];
      v = (((d3 * 256.0 + d2) * 256.0 + d1) * 256.0 + d0) * (1.0 / 16777216.0);
    } else {
      v = (double)J.Z[i];
      if (J.Zp0) v += (double)J.Zp0[i];
      if (J.Zp1) v += (double)J.Zp1[i];
      if (J.Zp2) v += (double)J.Zp2[i];
    }
    if (P.dodrop) v = (J.msk[i] >= 0.5f) ? 2.0 * (v + bb) : 0.0;
    s += v;
    s2 += v * v;
  }
  sm[rg][li] = s;
  sq[rg][li] = s2;
  __syncthreads();
  if (rg == 0) {
    double S = sm[0][li] + sm[1][li] + sm[2][li] + sm[3][li];
    double S2 = sq[0][li] + sq[1][li] + sq[2][li] + sq[3][li];
    size_t o = ((size_t)(z * 8 + blockIdx.y) * 2) * HIDC + col;
    P.ppart[o] = S;
    P.ppart[o + HIDC] = S2;
  }
}

__global__ __launch_bounds__(256) void k_stats_fin(const double* __restrict__ ppart,
                                                   double* __restrict__ stats) {
  const int z = blockIdx.z;
  const int c = blockIdx.x * 256 + threadIdx.x;
  double S = 0.0, S2 = 0.0;
#pragma unroll
  for (int y = 0; y < 8; ++y) {
    size_t o = ((size_t)(z * 8 + y) * 2) * HIDC + c;
    S += ppart[o];
    S2 += ppart[o + HIDC];
  }
  double m = S / 512.0;
  double var = S2 / 512.0 - m * m;
  stats[z * 2 * HIDC + c] = m;
  stats[z * 2 * HIDC + HIDC + c] = 1.0 / sqrt(var + 1e-5);
}

// ---------------------------------------------------------------------------
// BN (+optional dropout) + hardtanh, fp64 math; dual-path via grid.z.
// Optional conv slice at blockIdx.z==2 (second half of w3 conversion).
struct BnJob { float* Z; const float* Zp0; const float* Zp1; const float* Zp2;
               const float* Zp3; void* aux; const float* msk; int auxmode; int digitmode; };
struct Bn2 {
  BnJob j[2];
  const double* stats;
  const float* g; const float* be; const float* bias;
  int dodrop;
  const float* wsrc; _Float16* wvdst; char* s8dst;
};

__global__ __launch_bounds__(256) void k_bn2(Bn2 P) {
  const int z = blockIdx.z;
  if (z == 2) {
    // conv(w3) second half: vec8 [2359296, 4718592)
    int bid = blockIdx.x;  // 0..3071
    for (int i = 0; i < 3; ++i) {
      size_t g8 = 2359296ull + ((size_t)bid * 3 + i) * 256 + threadIdx.x;  // 3072*3*256
      conv8(P.wsrc, P.wvdst, P.s8dst, g8 * 8);
    }
    return;
  }
  BnJob J = z ? P.j[1] : P.j[0];
  const double* m_arr = P.stats + (size_t)z * 2 * HIDC;
  const double* r_arr = m_arr + HIDC;
  int idx = blockIdx.x * 256 + threadIdx.x;  // 512*1536 float4 positions
  int row = idx / 1536;
  int c4 = (idx - row * 1536) * 4;
  size_t base = (size_t)row * HIDC + c4;
  double vv[4];
  if (J.digitmode) {
    float4 d0 = *(const float4*)(J.Zp0 + base);
    float4 d1 = *(const float4*)(J.Zp1 + base);
    float4 d2 = *(const float4*)(J.Zp2 + base);
    float4 d3 = *(const float4*)(J.Zp3 + base);
    const float* p0 = &d0.x;
    const float* p1 = &d1.x;
    const float* p2 = &d2.x;
    const float* p3 = &d3.x;
#pragma unroll
    for (int e = 0; e < 4; ++e)
      vv[e] = ((((double)p3[e] * 256.0 + (double)p2[e]) * 256.0 + (double)p1[e]) * 256.0 +
               (double)p0[e]) * (1.0 / 16777216.0);
  } else {
    float4 zv = *(const float4*)(J.Z + base);
    vv[0] = zv.x; vv[1] = zv.y; vv[2] = zv.z; vv[3] = zv.w;
    if (J.Zp0) {
      float4 t4 = *(const float4*)(J.Zp0 + base);
      vv[0] += t4.x; vv[1] += t4.y; vv[2] += t4.z; vv[3] += t4.w;
    }
    if (J.Zp1) {
      float4 t4 = *(const float4*)(J.Zp1 + base);
      vv[0] += t4.x; vv[1] += t4.y; vv[2] += t4.z; vv[3] += t4.w;
    }
    if (J.Zp2) {
      float4 t4 = *(const float4*)(J.Zp2 + base);
      vv[0] += t4.x; vv[1] += t4.y; vv[2] += t4.z; vv[3] += t4.w;
    }
  }
  float mk[4] = {1.f, 1.f, 1.f, 1.f};
  if (P.dodrop) {
    float4 t4 = *(const float4*)(J.msk + base);
    mk[0] = t4.x; mk[1] = t4.y; mk[2] = t4.z; mk[3] = t4.w;
  }
  float o[4];
  f16x4 a4;
  int sbits = 0;
#pragma unroll
  for (int e = 0; e < 4; ++e) {
    int c = c4 + e;
    double v = vv[e];
    if (P.dodrop) v = (mk[e] >= 0.5f) ? 2.0 * (v + (double)P.bias[c]) : 0.0;
    double bnv = (double)P.g[c] * ((v - m_arr[c]) * r_arr[c]) + (double)P.be[c];
    bnv = bnv > 1.0 ? 1.0 : (bnv < -1.0 ? -1.0 : bnv);
    o[e] = (float)bnv;
    char sg = bnv > 0.0 ? 1 : (bnv < 0.0 ? -1 : 0);
    sbits |= ((int)(unsigned char)sg) << (8 * e);
    a4[e] = (_Float16)o[e];
  }
  float4 ov = {o[0], o[1], o[2], o[3]};
  *(float4*)(J.Z + base) = ov;
  if (J.auxmode == 0) *(int*)((char*)J.aux + base) = sbits;
  if (J.auxmode == 1) *(f16x4*)((_Float16*)J.aux + base) = a4;
}

// ---------------------------------------------------------------------------
// Head: out = Bout3 @ w4^T + b4 (512x10, K=6144) + log_softmax, one block/row.
__global__ __launch_bounds__(256) void k_head(const float* __restrict__ B3,
                                              const float* __restrict__ w4,
                                              const float* __restrict__ b4,
                                              float* __restrict__ out,
                                              float* __restrict__ logp) {
  const int row = blockIdx.x, t = threadIdx.x;
  float acc[10];
#pragma unroll
  for (int j = 0; j < 10; ++j) acc[j] = 0.f;
  const float* a = B3 + (size_t)row * HIDC;
  for (int k4 = t; k4 < 1536; k4 += 256) {
    float4 av = *(const float4*)(a + k4 * 4);
#pragma unroll
    for (int j = 0; j < 10; ++j) {
      float4 wv = *(const float4*)(w4 + (size_t)j * HIDC + k4 * 4);
      acc[j] += av.x * wv.x + av.y * wv.y + av.z * wv.z + av.w * wv.w;
    }
  }
#pragma unroll
  for (int j = 0; j < 10; ++j)
    for (int off = 32; off; off >>= 1) acc[j] += __shfl_down(acc[j], off);
  __shared__ float sred[4][10];
  int wid = t >> 6, ln = t & 63;
  if (ln == 0)
#pragma unroll
    for (int j = 0; j < 10; ++j) sred[wid][j] = acc[j];
  __syncthreads();
  if (t == 0) {
    double o[10];
    double mx = -1e300;
#pragma unroll
    for (int j = 0; j < 10; ++j) {
      o[j] = (double)sred[0][j] + sred[1][j] + sred[2][j] + sred[3][j] + (double)b4[j];
      mx = o[j] > mx ? o[j] : mx;
    }
    double s = 0.0;
#pragma unroll
    for (int j = 0; j < 10; ++j) s += exp(o[j] - mx);
    double l = log(s) + mx;
#pragma unroll
    for (int j = 0; j < 10; ++j) {
      out[row * 10 + j] = (float)o[j];
      logp[row * 10 + j] = (float)(o[j] - l);
    }
  }
}

// ===========================================================================
extern "C" void kernel_launch(void* const* d_in, const int* in_sizes, int n_in,
                              void* d_out, int out_size, void* d_ws, size_t ws_size,
                              hipStream_t stream) {
  const float* x   = (const float*)d_in[0];
  const float* mkb = (const float*)d_in[1];
  const float* mkr = (const float*)d_in[2];
  const float* w1  = (const float*)d_in[3];
  const float* w2  = (const float*)d_in[5];
  const float* w3  = (const float*)d_in[7];
  const float* b3  = (const float*)d_in[8];
  const float* w4  = (const float*)d_in[9];
  const float* b4  = (const float*)d_in[10];
  const float* g1  = (const float*)d_in[11]; const float* be1 = (const float*)d_in[12];
  const float* g2  = (const float*)d_in[13]; const float* be2 = (const float*)d_in[14];
  const float* g3  = (const float*)d_in[15]; const float* be3 = (const float*)d_in[16];

  float* outp = (float*)d_out;
  float* logp = outp;
  float* outo = outp + 5120;
  float* B1 = outp + 10240;
  float* R1 = outp + 3155968;
  float* B2 = outp + 6301696;
  float* R2 = outp + 9447424;
  float* B3 = outp + 12593152;
  float* R3 = outp + 15738880;

  char* ws = (char*)d_ws;
  _Float16* xh  = (_Float16*)(ws + OFF_XH);
  char* a8      = (char*)(ws + OFF_A8S1);
  char* s1      = (char*)(ws + OFF_A8S1 + 4ull * A8_STRIDE);
  char* sB8     = (char*)(ws + OFF_SB8);
  _Float16* rF  = (_Float16*)(ws + OFF_RF);
  double* stats = (double*)(ws + OFF_STATS);
  double* ppart = (double*)(ws + OFF_PPART);
  float* zpb    = (float*)(ws + OFF_ZPB);
  float* zpr    = (float*)(ws + OFF_ZPR);
  float* zpr2   = (float*)(ws + OFF_ZPR2);
  float* zpr3   = (float*)(ws + OFF_ZPR3);
  _Float16* w1v = (_Float16*)(ws + OFF_W1V);
  _Float16* wv  = (_Float16*)(ws + OFF_WV);
  char* ws8     = (char*)(ws + OFF_WS8);

  // ---- prep (x-quant + w1 convert, merged) ----
  k_prep_all<<<23296, 256, 0, stream>>>(x, w1, a8, xh, s1, w1v);
  // ---- layer 1 GEMMs + conv(w2) merged: z0-3 digit i8, z4 f16 real, z5 conv ----
  {
    Mix6 P{};
    P.j[0] = {a8,                 s1, zpb,  896, 0, 7, 1};
    P.j[1] = {a8 + A8_STRIDE,     s1, zpr,  896, 0, 7, 1};
    P.j[2] = {a8 + 2 * A8_STRIDE, s1, zpr2, 896, 0, 7, 1};
    P.j[3] = {a8 + 3 * A8_STRIDE, s1, zpr3, 896, 0, 7, 1};
    P.j[4] = {xh, w1v, R1, 832, 0, 13, 0};
    P.j[5] = {w2, wv, (float*)ws8, 0, 0, 0, 2};  // conv(w2)
    k_gemm_mix<<<dim3(48, 4, 6), 256, 0, stream>>>(P);
  }
  {
    St2 S{};
    S.j[0] = {zpb, zpr, zpr2, zpr3, nullptr, 1};   // digit combine
    S.j[1] = {R1, nullptr, nullptr, nullptr, nullptr, 0};
    S.bias = nullptr; S.dodrop = 0; S.ppart = ppart;
    k_stats_part<<<dim3(96, 8, 2), 256, 0, stream>>>(S);
    k_stats_fin<<<dim3(24, 1, 2), 256, 0, stream>>>(ppart, stats);
    Bn2 B{};
    B.j[0] = {B1, zpb, zpr, zpr2, zpr3, sB8, nullptr, 0, 1};  // digit, write B1
    B.j[1] = {R1, nullptr, nullptr, nullptr, nullptr, rF, nullptr, 1, 0};
    B.stats = stats; B.g = g1; B.be = be1; B.bias = nullptr; B.dodrop = 0;
    k_bn2<<<dim3(3072, 1, 2), 256, 0, stream>>>(B);
  }
  // ---- layer 2 (GEMM reads w2's converted buffers; conv(w3) rides on stats/bn) ----
  {
    Mix6 P{};
    P.j[0] = {sB8, ws8, B2,  HIDC, 0,    24, 1};
    P.j[1] = {sB8, ws8, zpb, HIDC, 3072, 24, 1};
    P.j[2] = {rF,  wv,  R2,  HIDC, 0,    48, 0};
    P.j[3] = {rF,  wv,  zpr, HIDC, 3072, 48, 0};
    k_gemm_mix<<<dim3(48, 4, 4), 256, 0, stream>>>(P);
  }
  {
    St2 S{};
    S.j[0] = {B2, zpb, nullptr, nullptr, nullptr, 0};
    S.j[1] = {R2, zpr, nullptr, nullptr, nullptr, 0};
    S.bias = nullptr; S.dodrop = 0; S.ppart = ppart;
    S.wsrc = w3; S.wvdst = wv; S.s8dst = ws8;
    k_stats_part<<<dim3(96, 8, 3), 256, 0, stream>>>(S);  // z=2: conv(w3) 1st half
    k_stats_fin<<<dim3(24, 1, 2), 256, 0, stream>>>(ppart, stats);
    Bn2 B{};
    B.j[0] = {B2, zpb, nullptr, nullptr, nullptr, sB8, nullptr, 0, 0};
    B.j[1] = {R2, zpr, nullptr, nullptr, nullptr, rF, nullptr, 1, 0};
    B.stats = stats; B.g = g2; B.be = be2; B.bias = nullptr; B.dodrop = 0;
    B.wsrc = w3; B.wvdst = wv; B.s8dst = ws8;
    k_bn2<<<dim3(3072, 1, 3), 256, 0, stream>>>(B);  // z=2: conv(w3) 2nd half
  }
  // ---- layer 3 ----
  {
    Mix6 P{};
    P.j[0] = {sB8, ws8, B3,  HIDC, 0,    24, 1};
    P.j[1] = {sB8, ws8, zpb, HIDC, 3072, 24, 1};
    P.j[2] = {rF,  wv,  R3,  HIDC, 0,    48, 0};
    P.j[3] = {rF,  wv,  zpr, HIDC, 3072, 48, 0};
    k_gemm_mix<<<dim3(48, 4, 4), 256, 0, stream>>>(P);
  }
  {
    St2 S{};
    S.j[0] = {B3, zpb, nullptr, nullptr, mkb, 0};
    S.j[1] = {R3, zpr, nullptr, nullptr, mkr, 0};
    S.bias = b3; S.dodrop = 1; S.ppart = ppart;
    k_stats_part<<<dim3(96, 8, 2), 256, 0, stream>>>(S);
    k_stats_fin<<<dim3(24, 1, 2), 256, 0, stream>>>(ppart, stats);
    Bn2 B{};
    B.j[0] = {B3, zpb, nullptr, nullptr, nullptr, nullptr, mkb, 2, 0};
    B.j[1] = {R3, zpr, nullptr, nullptr, nullptr, nullptr, mkr, 2, 0};
    B.stats = stats; B.g = g3; B.be = be3; B.bias = b3; B.dodrop = 1;
    k_bn2<<<dim3(3072, 1, 2), 256, 0, stream>>>(B);
  }
  // ---- head ----
  k_head<<<512, 256, 0, stream>>>(B3, w4, b4, outo, logp);
}

// Round 14
// 453.522 us; speedup vs baseline: 1.0953x; 1.0953x over previous
//
#include <hip/hip_runtime.h>

// Binarized MLP forward (512x784 -> 3x6144 -> 10), dual binary/real paths.
// Round 14: revert to r12 structure (best, 460us) -- r13's conv-merge
// regressed (conv job under-parallel in GEMM dispatch; glue dispatches are
// BW-bound so riding conv on them conserves time). Only r13 piece kept:
// merged prep launch. GEMM kernel r11-validated (counted-vmcnt dbuf + T2
// swizzle + setprio, bank-conflicts=0).
//
// Precision plan (validated r1-r12):
//  - layer1 binary: exact i8-digit MFMA, fp64 recombination fused in stats/bn
//  - layer2/3 binary: i8 MFMA K=64, EXACT (i32 sums <= 6144, fp32-exact)
//  - real path: fp16 MFMA (error ~1e-3 << 2% thresholds)
//  - all batch-norm stats and normalization in fp64

typedef _Float16 f16x8 __attribute__((ext_vector_type(8)));
typedef _Float16 f16x4 __attribute__((ext_vector_type(4)));
typedef float f32x4 __attribute__((ext_vector_type(4)));
typedef int i32x4 __attribute__((ext_vector_type(4)));

#define MFMA16(a, b, c) __builtin_amdgcn_mfma_f32_16x16x32_f16((a), (b), (c), 0, 0, 0)
#define MFMAI8K64(a, b, c) __builtin_amdgcn_mfma_i32_16x16x64_i8((a), (b), (c), 0, 0, 0)

#define HIDC 6144
#define BATCH 512

// ---- workspace layout (bytes) ----
#define OFF_XH    0ull          // 512x832 fp16                    851,968
#define OFF_A8S1  851968ull     // a8 4x(512x896) + s1 6144x896   7,340,032
#define OFF_SB8   13434880ull   // 512x6144 i8 sign acts         3,145,728
#define OFF_RF    16580608ull   // 512x6144 fp16 real acts       6,291,456
#define OFF_STATS 22872064ull   // 4x6144 fp64                     196,608
#define OFF_PPART 23068672ull   // 2x8x2x6144 fp64               1,572,864
#define OFF_ZPB   24641536ull   // 512x6144 fp32 partial/D0     12,582,912
#define OFF_ZPR   37224448ull   // 512x6144 fp32 partial/D1     12,582,912
#define OFF_ZPR2  49807360ull   // 512x6144 fp32 D2             12,582,912
#define OFF_ZPR3  62390272ull   // 512x6144 fp32 D3             12,582,912
#define OFF_W1V   74973184ull   // 6144x832 fp16                10,223,616
#define OFF_WV    85196800ull   // 6144x6144 fp16               75,497,472
#define OFF_WS8   160694272ull  // 6144x6144 i8 sign weights    37,748,736
#define WS_NEED   198443008ull

#define A8_STRIDE 458752ull     // 512*896 bytes per digit plane

// ---------------------------------------------------------------------------
__device__ __forceinline__ void load_lds16(const void* g, char* lds) {
  __builtin_amdgcn_global_load_lds((const __attribute__((address_space(1))) void*)g,
                                   (__attribute__((address_space(3))) void*)lds, 16, 0, 0);
}

// ---------------------------------------------------------------------------
// merged prep: blocks [0,1792): x -> xh + digit planes; [1792,23296): w1 -> s1,w1v
__global__ __launch_bounds__(256) void k_prep_all(const float* __restrict__ x,
                                                  const float* __restrict__ w,
                                                  char* __restrict__ a8,
                                                  _Float16* __restrict__ xh,
                                                  char* __restrict__ s1,
                                                  _Float16* __restrict__ w1v) {
  if (blockIdx.x < 1792) {
    int idx = blockIdx.x * 256 + threadIdx.x;  // 512*896
    if (idx >= 512 * 896) return;
    int row = idx / 896, k = idx - row * 896;
    float v = (k < 784) ? x[(size_t)row * 784 + k] : 0.f;
    int q = (int)lrintf(v * 16777216.0f);
    int d0 = ((q + 128) & 255) - 128; q = (q - d0) >> 8;
    int d1 = ((q + 128) & 255) - 128; q = (q - d1) >> 8;
    int d2 = ((q + 128) & 255) - 128; q = (q - d2) >> 8;
    a8[idx] = (char)d0;
    a8[A8_STRIDE + idx] = (char)d1;
    a8[2 * A8_STRIDE + idx] = (char)d2;
    a8[3 * A8_STRIDE + idx] = (char)q;  // |q| <= 9
    if (k < 832) xh[(size_t)row * 832 + k] = (_Float16)v;
  } else {
    int idx = (blockIdx.x - 1792) * 256 + threadIdx.x;  // 6144*896
    if (idx >= 6144 * 896) return;
    int r = idx / 896, k = idx - r * 896;
    float v = (k < 784) ? w[(size_t)r * 784 + k] : 0.f;
    s1[idx] = v > 0.f ? 1 : (v < 0.f ? -1 : 0);
    if (k < 832) w1v[(size_t)r * 832 + k] = (_Float16)v;
  }
}

// ---------------------------------------------------------------------------
// w (6144x6144 fp32) -> Wv (fp16 value), Ws8 (i8 sign)
__global__ __launch_bounds__(256) void k_conv_w23(const float* __restrict__ w,
                                                  _Float16* __restrict__ wv,
                                                  char* __restrict__ ws8) {
  int idx = blockIdx.x * 256 + threadIdx.x;  // 6144*768 groups of 8
  size_t o8 = (size_t)idx * 8;
  const float* s = w + o8;
  float4 v0 = *(const float4*)s;
  float4 v1 = *(const float4*)(s + 4);
  float a[8] = {v0.x, v0.y, v0.z, v0.w, v1.x, v1.y, v1.z, v1.w};
  f16x8 hv;
  unsigned long long sbits = 0;
#pragma unroll
  for (int e = 0; e < 8; ++e) {
    hv[e] = (_Float16)a[e];
    char sg = a[e] > 0.f ? 1 : (a[e] < 0.f ? -1 : 0);
    sbits |= ((unsigned long long)(unsigned char)sg) << (8 * e);
  }
  *(f16x8*)(wv + o8) = hv;
  *(unsigned long long*)(ws8 + o8) = sbits;
}

// ---------------------------------------------------------------------------
// Mixed GEMM dispatch, 128x128 tile, 256 threads (4 waves 2x2), double-
// buffered LDS, counted-vmcnt pipeline, XOR-swizzled LDS (r11-validated).
//   is8=1: BK=128 i8 GEMM ; is8=0: BK=64 f16 GEMM
struct MixJob {
  const void* A;
  const void* B;
  float* C;
  int K;
  int kstart;
  int ksteps;
  int is8;
};
struct Mix6 { MixJob j[6]; };

__global__ __launch_bounds__(256) void k_gemm_mix(Mix6 P) {
  __shared__ __align__(16) char smem[65536];  // 2 x {A@0 16K, B@16384 16K}
  MixJob J = P.j[0];
  if (blockIdx.z == 1) J = P.j[1];
  if (blockIdx.z == 2) J = P.j[2];
  if (blockIdx.z == 3) J = P.j[3];
  if (blockIdx.z == 4) J = P.j[4];
  if (blockIdx.z == 5) J = P.j[5];
  const int t = threadIdx.x;
  const int lane = t & 63, wid = t >> 6;
  const int wm = wid >> 1, wn = wid & 1;
  const int bn = blockIdx.x, bm = blockIdx.y;
  const size_t K = (size_t)J.K;
  const int nt = J.ksteps;

  if (J.is8) {
    // ---------------- i8 path (BK=128) ----------------
    const char* A = (const char*)J.A;
    const char* B = (const char*)J.B;
    i32x4 acc[4][4];
#pragma unroll
    for (int mf = 0; mf < 4; ++mf)
#pragma unroll
      for (int nf = 0; nf < 4; ++nf) acc[mf][nf] = (i32x4){0, 0, 0, 0};

    auto stage = [&](char* dst, int k0) {
#pragma unroll
      for (int i = 0; i < 4; ++i) {
        int p = i * 256 + t;
        int r = p >> 3, c = p & 7;
        int cs = c ^ (r & 7);
        load_lds16(A + (size_t)(bm * 128 + r) * K + k0 + cs * 16, dst + p * 16);
      }
#pragma unroll
      for (int i = 0; i < 4; ++i) {
        int p = i * 256 + t;
        int r = p >> 3, c = p & 7;
        int cs = c ^ (r & 7);
        load_lds16(B + (size_t)(bn * 128 + r) * K + k0 + cs * 16, dst + 16384 + p * 16);
      }
    };

    stage(smem, J.kstart);
    for (int kt = 0; kt < nt; ++kt) {
      char* cbuf = smem + (kt & 1) * 32768;
      char* nbuf = smem + ((kt + 1) & 1) * 32768;
      if (kt + 1 < nt) {
        stage(nbuf, J.kstart + (kt + 1) * 128);
        asm volatile("s_waitcnt vmcnt(8)" ::: "memory");
      } else {
        asm volatile("s_waitcnt vmcnt(0)" ::: "memory");
      }
      __builtin_amdgcn_s_barrier();
      __builtin_amdgcn_s_setprio(1);
#pragma unroll
      for (int kk = 0; kk < 2; ++kk) {  // two K=64 halves of BK=128
        i32x4 av[4], bv[4];
#pragma unroll
        for (int mf = 0; mf < 4; ++mf) {
          int r = wm * 64 + mf * 16 + (lane & 15);
          int bo = (r * 128 + kk * 64 + (lane >> 4) * 16) ^ ((r & 7) << 4);
          av[mf] = *(const i32x4*)(cbuf + bo);
        }
#pragma unroll
        for (int nf = 0; nf < 4; ++nf) {
          int r = wn * 64 + nf * 16 + (lane & 15);
          int bo = (r * 128 + kk * 64 + (lane >> 4) * 16) ^ ((r & 7) << 4);
          bv[nf] = *(const i32x4*)(cbuf + 16384 + bo);
        }
#pragma unroll
        for (int mf = 0; mf < 4; ++mf)
#pragma unroll
          for (int nf = 0; nf < 4; ++nf) acc[mf][nf] = MFMAI8K64(av[mf], bv[nf], acc[mf][nf]);
      }
      __builtin_amdgcn_s_setprio(0);
      __builtin_amdgcn_s_barrier();
    }
#pragma unroll
    for (int mf = 0; mf < 4; ++mf)
#pragma unroll
      for (int nf = 0; nf < 4; ++nf) {
        int col = bn * 128 + wn * 64 + nf * 16 + (lane & 15);
        int row0 = bm * 128 + wm * 64 + mf * 16 + ((lane >> 4) << 2);
#pragma unroll
        for (int rr = 0; rr < 4; ++rr) {
          J.C[(size_t)(row0 + rr) * HIDC + col] = (float)acc[mf][nf][rr];  // exact (<2^24)
        }
      }
  } else {
    // ---------------- f16 path (BK=64) ----------------
    const _Float16* A = (const _Float16*)J.A;
    const _Float16* B = (const _Float16*)J.B;
    f32x4 acc[4][4];
#pragma unroll
    for (int mf = 0; mf < 4; ++mf)
#pragma unroll
      for (int nf = 0; nf < 4; ++nf) acc[mf][nf] = (f32x4){0.f, 0.f, 0.f, 0.f};

    auto stage = [&](char* dst, int k0) {
#pragma unroll
      for (int i = 0; i < 4; ++i) {
        int p = i * 256 + t;
        int r = p >> 3, c = p & 7;
        int cs = c ^ (r & 7);
        load_lds16(A + (size_t)(bm * 128 + r) * K + k0 + cs * 8, dst + p * 16);
      }
#pragma unroll
      for (int i = 0; i < 4; ++i) {
        int p = i * 256 + t;
        int r = p >> 3, c = p & 7;
        int cs = c ^ (r & 7);
        load_lds16(B + (size_t)(bn * 128 + r) * K + k0 + cs * 8, dst + 16384 + p * 16);
      }
    };

    stage(smem, J.kstart);
    for (int kt = 0; kt < nt; ++kt) {
      char* cbuf = smem + (kt & 1) * 32768;
      char* nbuf = smem + ((kt + 1) & 1) * 32768;
      if (kt + 1 < nt) {
        stage(nbuf, J.kstart + (kt + 1) * 64);
        asm volatile("s_waitcnt vmcnt(8)" ::: "memory");
      } else {
        asm volatile("s_waitcnt vmcnt(0)" ::: "memory");
      }
      __builtin_amdgcn_s_barrier();
      __builtin_amdgcn_s_setprio(1);
#pragma unroll
      for (int kk = 0; kk < 2; ++kk) {
        f16x8 av[4], bv[4];
#pragma unroll
        for (int mf = 0; mf < 4; ++mf) {
          int r = wm * 64 + mf * 16 + (lane & 15);
          int bo = (r * 128 + kk * 64 + (lane >> 4) * 16) ^ ((r & 7) << 4);
          av[mf] = *(const f16x8*)(cbuf + bo);
        }
#pragma unroll
        for (int nf = 0; nf < 4; ++nf) {
          int r = wn * 64 + nf * 16 + (lane & 15);
          int bo = (r * 128 + kk * 64 + (lane >> 4) * 16) ^ ((r & 7) << 4);
          bv[nf] = *(const f16x8*)(cbuf + 16384 + bo);
        }
#pragma unroll
        for (int mf = 0; mf < 4; ++mf)
#pragma unroll
          for (int nf = 0; nf < 4; ++nf) acc[mf][nf] = MFMA16(av[mf], bv[nf], acc[mf][nf]);
      }
      __builtin_amdgcn_s_setprio(0);
      __builtin_amdgcn_s_barrier();
    }
#pragma unroll
    for (int mf = 0; mf < 4; ++mf)
#pragma unroll
      for (int nf = 0; nf < 4; ++nf) {
        int col = bn * 128 + wn * 64 + nf * 16 + (lane & 15);
        int row0 = bm * 128 + wm * 64 + mf * 16 + ((lane >> 4) << 2);
#pragma unroll
        for (int rr = 0; rr < 4; ++rr) {
          J.C[(size_t)(row0 + rr) * HIDC + col] = acc[mf][nf][rr];
        }
      }
  }
}

// ---------------------------------------------------------------------------
// Two-stage per-column stats (mean, rstd over 512 rows), fp64.
// digitmode: v = (((Z3*256+Z2)*256+Z1)*256+Z0) * 2^-24 (planes in Z,Zp0..2)
struct StJob { const float* Z; const float* Zp0; const float* Zp1; const float* Zp2;
               const float* msk; int digitmode; };
struct St2 { StJob j[2]; const float* bias; int dodrop; double* ppart; };

__global__ __launch_bounds__(256) void k_stats_part(St2 P) {
  __shared__ double sm[4][64];
  __shared__ double sq[4][64];
  const int z = blockIdx.z;
  StJob J = z ? P.j[1] : P.j[0];
  const int li = threadIdx.x & 63, rg = threadIdx.x >> 6;
  const int col = blockIdx.x * 64 + li;
  const double bb = P.dodrop ? (double)P.bias[col] : 0.0;
  double s = 0.0, s2 = 0.0;
#pragma unroll 4
  for (int rr = 0; rr < 16; ++rr) {
    int r = blockIdx.y * 64 + rg * 16 + rr;
    size_t i = (size_t)r * HIDC + col;
    double v;
    if (J.digitmode) {
      double d0 = (double)J.Z[i], d1 = (double)J.Zp0[i];
      double d2 = (double)J.Zp1[i], d3 = (double)J.Zp2[i];
      v = (((d3 * 256.0 + d2) * 256.0 + d1) * 256.0 + d0) * (1.0 / 16777216.0);
    } else {
      v = (double)J.Z[i];
      if (J.Zp0) v += (double)J.Zp0[i];
      if (J.Zp1) v += (double)J.Zp1[i];
      if (J.Zp2) v += (double)J.Zp2[i];
    }
    if (P.dodrop) v = (J.msk[i] >= 0.5f) ? 2.0 * (v + bb) : 0.0;
    s += v;
    s2 += v * v;
  }
  sm[rg][li] = s;
  sq[rg][li] = s2;
  __syncthreads();
  if (rg == 0) {
    double S = sm[0][li] + sm[1][li] + sm[2][li] + sm[3][li];
    double S2 = sq[0][li] + sq[1][li] + sq[2][li] + sq[3][li];
    size_t o = ((size_t)(z * 8 + blockIdx.y) * 2) * HIDC + col;
    P.ppart[o] = S;
    P.ppart[o + HIDC] = S2;
  }
}

__global__ __launch_bounds__(256) void k_stats_fin(const double* __restrict__ ppart,
                                                   double* __restrict__ stats) {
  const int z = blockIdx.z;
  const int c = blockIdx.x * 256 + threadIdx.x;
  double S = 0.0, S2 = 0.0;
#pragma unroll
  for (int y = 0; y < 8; ++y) {
    size_t o = ((size_t)(z * 8 + y) * 2) * HIDC + c;
    S += ppart[o];
    S2 += ppart[o + HIDC];
  }
  double m = S / 512.0;
  double var = S2 / 512.0 - m * m;
  stats[z * 2 * HIDC + c] = m;
  stats[z * 2 * HIDC + HIDC + c] = 1.0 / sqrt(var + 1e-5);
}

// ---------------------------------------------------------------------------
// BN (+optional dropout) + hardtanh, fp64 math; dual-path via grid.z.
// digitmode: v from 4 planes Zp0..Zp3 (exact integers), Z is WRITE-ONLY.
// auxmode: 0 -> aux (i8) = sign(out) ; 1 -> aux (f16) = out ; 2 -> none.
struct BnJob { float* Z; const float* Zp0; const float* Zp1; const float* Zp2;
               const float* Zp3; void* aux; const float* msk; int auxmode; int digitmode; };
struct Bn2 {
  BnJob j[2];
  const double* stats;
  const float* g; const float* be; const float* bias;
  int dodrop;
};

__global__ __launch_bounds__(256) void k_bn2(Bn2 P) {
  const int z = blockIdx.z;
  BnJob J = z ? P.j[1] : P.j[0];
  const double* m_arr = P.stats + (size_t)z * 2 * HIDC;
  const double* r_arr = m_arr + HIDC;
  int idx = blockIdx.x * 256 + threadIdx.x;  // 512*1536 float4 positions
  int row = idx / 1536;
  int c4 = (idx - row * 1536) * 4;
  size_t base = (size_t)row * HIDC + c4;
  double vv[4];
  if (J.digitmode) {
    float4 d0 = *(const float4*)(J.Zp0 + base);
    float4 d1 = *(const float4*)(J.Zp1 + base);
    float4 d2 = *(const float4*)(J.Zp2 + base);
    float4 d3 = *(const float4*)(J.Zp3 + base);
    const float* p0 = &d0.x;
    const float* p1 = &d1.x;
    const float* p2 = &d2.x;
    const float* p3 = &d3.x;
#pragma unroll
    for (int e = 0; e < 4; ++e)
      vv[e] = ((((double)p3[e] * 256.0 + (double)p2[e]) * 256.0 + (double)p1[e]) * 256.0 +
               (double)p0[e]) * (1.0 / 16777216.0);
  } else {
    float4 zv = *(const float4*)(J.Z + base);
    vv[0] = zv.x; vv[1] = zv.y; vv[2] = zv.z; vv[3] = zv.w;
    if (J.Zp0) {
      float4 t4 = *(const float4*)(J.Zp0 + base);
      vv[0] += t4.x; vv[1] += t4.y; vv[2] += t4.z; vv[3] += t4.w;
    }
    if (J.Zp1) {
      float4 t4 = *(const float4*)(J.Zp1 + base);
      vv[0] += t4.x; vv[1] += t4.y; vv[2] += t4.z; vv[3] += t4.w;
    }
    if (J.Zp2) {
      float4 t4 = *(const float4*)(J.Zp2 + base);
      vv[0] += t4.x; vv[1] += t4.y; vv[2] += t4.z; vv[3] += t4.w;
    }
  }
  float mk[4] = {1.f, 1.f, 1.f, 1.f};
  if (P.dodrop) {
    float4 t4 = *(const float4*)(J.msk + base);
    mk[0] = t4.x; mk[1] = t4.y; mk[2] = t4.z; mk[3] = t4.w;
  }
  float o[4];
  f16x4 a4;
  int sbits = 0;
#pragma unroll
  for (int e = 0; e < 4; ++e) {
    int c = c4 + e;
    double v = vv[e];
    if (P.dodrop) v = (mk[e] >= 0.5f) ? 2.0 * (v + (double)P.bias[c]) : 0.0;
    double bnv = (double)P.g[c] * ((v - m_arr[c]) * r_arr[c]) + (double)P.be[c];
    bnv = bnv > 1.0 ? 1.0 : (bnv < -1.0 ? -1.0 : bnv);
    o[e] = (float)bnv;
    char sg = bnv > 0.0 ? 1 : (bnv < 0.0 ? -1 : 0);
    sbits |= ((int)(unsigned char)sg) << (8 * e);
    a4[e] = (_Float16)o[e];
  }
  float4 ov = {o[0], o[1], o[2], o[3]};
  *(float4*)(J.Z + base) = ov;
  if (J.auxmode == 0) *(int*)((char*)J.aux + base) = sbits;
  if (J.auxmode == 1) *(f16x4*)((_Float16*)J.aux + base) = a4;
}

// ---------------------------------------------------------------------------
// Head: out = Bout3 @ w4^T + b4 (512x10, K=6144) + log_softmax, one block/row.
__global__ __launch_bounds__(256) void k_head(const float* __restrict__ B3,
                                              const float* __restrict__ w4,
                                              const float* __restrict__ b4,
                                              float* __restrict__ out,
                                              float* __restrict__ logp) {
  const int row = blockIdx.x, t = threadIdx.x;
  float acc[10];
#pragma unroll
  for (int j = 0; j < 10; ++j) acc[j] = 0.f;
  const float* a = B3 + (size_t)row * HIDC;
  for (int k4 = t; k4 < 1536; k4 += 256) {
    float4 av = *(const float4*)(a + k4 * 4);
#pragma unroll
    for (int j = 0; j < 10; ++j) {
      float4 wv = *(const float4*)(w4 + (size_t)j * HIDC + k4 * 4);
      acc[j] += av.x * wv.x + av.y * wv.y + av.z * wv.z + av.w * wv.w;
    }
  }
#pragma unroll
  for (int j = 0; j < 10; ++j)
    for (int off = 32; off; off >>= 1) acc[j] += __shfl_down(acc[j], off);
  __shared__ float sred[4][10];
  int wid = t >> 6, ln = t & 63;
  if (ln == 0)
#pragma unroll
    for (int j = 0; j < 10; ++j) sred[wid][j] = acc[j];
  __syncthreads();
  if (t == 0) {
    double o[10];
    double mx = -1e300;
#pragma unroll
    for (int j = 0; j < 10; ++j) {
      o[j] = (double)sred[0][j] + sred[1][j] + sred[2][j] + sred[3][j] + (double)b4[j];
      mx = o[j] > mx ? o[j] : mx;
    }
    double s = 0.0;
#pragma unroll
    for (int j = 0; j < 10; ++j) s += exp(o[j] - mx);
    double l = log(s) + mx;
#pragma unroll
    for (int j = 0; j < 10; ++j) {
      out[row * 10 + j] = (float)o[j];
      logp[row * 10 + j] = (float)(o[j] - l);
    }
  }
}

// ===========================================================================
extern "C" void kernel_launch(void* const* d_in, const int* in_sizes, int n_in,
                              void* d_out, int out_size, void* d_ws, size_t ws_size,
                              hipStream_t stream) {
  const float* x   = (const float*)d_in[0];
  const float* mkb = (const float*)d_in[1];
  const float* mkr = (const float*)d_in[2];
  const float* w1  = (const float*)d_in[3];
  const float* w2  = (const float*)d_in[5];
  const float* w3  = (const float*)d_in[7];
  const float* b3  = (const float*)d_in[8];
  const float* w4  = (const float*)d_in[9];
  const float* b4  = (const float*)d_in[10];
  const float* g1  = (const float*)d_in[11]; const float* be1 = (const float*)d_in[12];
  const float* g2  = (const float*)d_in[13]; const float* be2 = (const float*)d_in[14];
  const float* g3  = (const float*)d_in[15]; const float* be3 = (const float*)d_in[16];

  float* outp = (float*)d_out;
  float* logp = outp;
  float* outo = outp + 5120;
  float* B1 = outp + 10240;
  float* R1 = outp + 3155968;
  float* B2 = outp + 6301696;
  float* R2 = outp + 9447424;
  float* B3 = outp + 12593152;
  float* R3 = outp + 15738880;

  char* ws = (char*)d_ws;
  _Float16* xh  = (_Float16*)(ws + OFF_XH);
  char* a8      = (char*)(ws + OFF_A8S1);
  char* s1      = (char*)(ws + OFF_A8S1 + 4ull * A8_STRIDE);
  char* sB8     = (char*)(ws + OFF_SB8);
  _Float16* rF  = (_Float16*)(ws + OFF_RF);
  double* stats = (double*)(ws + OFF_STATS);
  double* ppart = (double*)(ws + OFF_PPART);
  float* zpb    = (float*)(ws + OFF_ZPB);
  float* zpr    = (float*)(ws + OFF_ZPR);
  float* zpr2   = (float*)(ws + OFF_ZPR2);
  float* zpr3   = (float*)(ws + OFF_ZPR3);
  _Float16* w1v = (_Float16*)(ws + OFF_W1V);
  _Float16* wv  = (_Float16*)(ws + OFF_WV);
  char* ws8     = (char*)(ws + OFF_WS8);

  // ---- prep (x-quant + w1 convert, merged) ----
  k_prep_all<<<23296, 256, 0, stream>>>(x, w1, a8, xh, s1, w1v);
  // ---- layer 1 GEMMs: 4 digit i8 jobs (K=896, 7 steps) + real f16 (13 steps) ----
  {
    Mix6 P{};
    P.j[0] = {a8,                 s1, zpb,  896, 0, 7, 1};
    P.j[1] = {a8 + A8_STRIDE,     s1, zpr,  896, 0, 7, 1};
    P.j[2] = {a8 + 2 * A8_STRIDE, s1, zpr2, 896, 0, 7, 1};
    P.j[3] = {a8 + 3 * A8_STRIDE, s1, zpr3, 896, 0, 7, 1};
    P.j[4] = {xh, w1v, R1, 832, 0, 13, 0};
    P.j[5] = P.j[4];
    k_gemm_mix<<<dim3(48, 4, 5), 256, 0, stream>>>(P);
  }
  {
    St2 S{};
    S.j[0] = {zpb, zpr, zpr2, zpr3, nullptr, 1};   // digit combine
    S.j[1] = {R1, nullptr, nullptr, nullptr, nullptr, 0};
    S.bias = nullptr; S.dodrop = 0; S.ppart = ppart;
    k_stats_part<<<dim3(96, 8, 2), 256, 0, stream>>>(S);
    k_stats_fin<<<dim3(24, 1, 2), 256, 0, stream>>>(ppart, stats);
    Bn2 B{};
    B.j[0] = {B1, zpb, zpr, zpr2, zpr3, sB8, nullptr, 0, 1};  // digit, write B1
    B.j[1] = {R1, nullptr, nullptr, nullptr, nullptr, rF, nullptr, 1, 0};
    B.stats = stats; B.g = g1; B.be = be1; B.bias = nullptr; B.dodrop = 0;
    k_bn2<<<dim3(3072, 1, 2), 256, 0, stream>>>(B);
  }
  // ---- layer 2 ----
  k_conv_w23<<<18432, 256, 0, stream>>>(w2, wv, ws8);
  {
    Mix6 P{};
    P.j[0] = {sB8, ws8, B2,  HIDC, 0,    24, 1};
    P.j[1] = {sB8, ws8, zpb, HIDC, 3072, 24, 1};
    P.j[2] = {rF,  wv,  R2,  HIDC, 0,    48, 0};
    P.j[3] = {rF,  wv,  zpr, HIDC, 3072, 48, 0};
    k_gemm_mix<<<dim3(48, 4, 4), 256, 0, stream>>>(P);
  }
  {
    St2 S{};
    S.j[0] = {B2, zpb, nullptr, nullptr, nullptr, 0};
    S.j[1] = {R2, zpr, nullptr, nullptr, nullptr, 0};
    S.bias = nullptr; S.dodrop = 0; S.ppart = ppart;
    k_stats_part<<<dim3(96, 8, 2), 256, 0, stream>>>(S);
    k_stats_fin<<<dim3(24, 1, 2), 256, 0, stream>>>(ppart, stats);
    Bn2 B{};
    B.j[0] = {B2, zpb, nullptr, nullptr, nullptr, sB8, nullptr, 0, 0};
    B.j[1] = {R2, zpr, nullptr, nullptr, nullptr, rF, nullptr, 1, 0};
    B.stats = stats; B.g = g2; B.be = be2; B.bias = nullptr; B.dodrop = 0;
    k_bn2<<<dim3(3072, 1, 2), 256, 0, stream>>>(B);
  }
  // ---- layer 3 ----
  k_conv_w23<<<18432, 256, 0, stream>>>(w3, wv, ws8);
  {
    Mix6 P{};
    P.j[0] = {sB8, ws8, B3,  HIDC, 0,    24, 1};
    P.j[1] = {sB8, ws8, zpb, HIDC, 3072, 24, 1};
    P.j[2] = {rF,  wv,  R3,  HIDC, 0,    48, 0};
    P.j[3] = {rF,  wv,  zpr, HIDC, 3072, 48, 0};
    k_gemm_mix<<<dim3(48, 4, 4), 256, 0, stream>>>(P);
  }
  {
    St2 S{};
    S.j[0] = {B3, zpb, nullptr, nullptr, mkb, 0};
    S.j[1] = {R3, zpr, nullptr, nullptr, mkr, 0};
    S.bias = b3; S.dodrop = 1; S.ppart = ppart;
    k_stats_part<<<dim3(96, 8, 2), 256, 0, stream>>>(S);
    k_stats_fin<<<dim3(24, 1, 2), 256, 0, stream>>>(ppart, stats);
    Bn2 B{};
    B.j[0] = {B3, zpb, nullptr, nullptr, nullptr, nullptr, mkb, 2, 0};
    B.j[1] = {R3, zpr, nullptr, nullptr, nullptr, nullptr, mkr, 2, 0};
    B.stats = stats; B.g = g3; B.be = be3; B.bias = b3; B.dodrop = 1;
    k_bn2<<<dim3(3072, 1, 2), 256, 0, stream>>>(B);
  }
  // ---- head ----
  k_head<<<512, 256, 0, stream>>>(B3, w4, b4, outo, logp);
}